// Round 1
// 142.608 us; speedup vs baseline: 1.1037x; 1.1037x over previous
//
#include <hip/hip_runtime.h>

// GENConv softmax-aggregation + MLP for MI355X (gfx950) — round 12.
//
// Round-11 counters (agg_mlp 57.3us): MfmaUtil 0.5, VALUBusy 36.5, HBM 15%,
// Occupancy 33%. Diagnosis: LDS 27.1KB/block -> only 6 blocks/CU resident;
// grid 1564 = 6x256+28, so 28 straggler blocks run SERIALLY after the first
// 1536 retire (uniform Poisson work -> simultaneous retire). Wall ~= 2x
// per-block time with 228 CUs idle in the second half; predicted occupancy
// under that model = 38%, measured 33% -> theory confirmed by counters.
// Round-12: union bins[] (dead after gather barrier) with hid[] (written
// only after it) -> LDS 26.9KB -> 17.7KB -> 8 blocks/CU (thread-capped),
// all 1564 blocks co-resident from t=0, no serial tail.
// __launch_bounds__(256,8) declares 8 waves/EU (VGPR=40 << 64 cap, safe).
//
// Math (passed r1-r11): msg = bf16(relu(x)+eps) bounded -> skip segment-max;
//   h[n,c] = sum exp(b*m)*m / sum exp(b*m);  out = relu(h@W1+b1)@W2+b2

#define N_NODES 100000
#define N_EDGES 1600000
#define DCH 32
#define HCH 64
#define EPS 1e-7f

#define NPB 256                       // nodes per coarse bucket (dst >> 8)
#define NB 391                        // ceil(100000/256)
#define CAPB 4544                     // mean 4092, +7 sigma
#define GSTRIDE 16
#define P1_BLOCKS 512
#define P1_THREADS 512
#define CHUNK 3125                    // 512 * 3125 = 1.6M exactly
#define SLOT 48                       // per-node LDS bin cap (P[Poi16>48]~1e-11)

typedef __attribute__((ext_vector_type(8))) short bf16x8;
typedef __attribute__((ext_vector_type(4))) float f32x4;

__device__ inline unsigned short f2b(float v) {   // fp32 -> bf16 RNE
    unsigned u = __float_as_uint(v);
    return (unsigned short)((u + 0x7FFFu + ((u >> 16) & 1u)) >> 16);
}

// ---------------------------------------------------------------------------
// Pass 1: bf16 msg table + weight frags + coarse-bucket partition via
// DIRECT scatter (no sort, no flush). LDS = 4 KB -> 32 waves/CU.
// ---------------------------------------------------------------------------
__global__ __launch_bounds__(P1_THREADS) void genconv_partition(
    const float* __restrict__ x,
    const int* __restrict__ eidx,     // [2E]: [0,E)=dst, [E,2E)=src
    const float* __restrict__ W1, const float* __restrict__ W2,
    int* __restrict__ gcnt,           // [NB*GSTRIDE] zeroed; bucket totals
    unsigned* __restrict__ buf,       // [NB*CAPB] packed src | localdst<<17
    unsigned short* __restrict__ msgb,
    unsigned short* __restrict__ W1f, unsigned short* __restrict__ W2f)
{
    __shared__ int hcnt[512];
    __shared__ int hcur[512];

    const int tid = threadIdx.x;

    // --- fused bf16 msg table: grid-stride float4 over x (800k float4) ---
    {
        const int nthreads = P1_BLOCKS * P1_THREADS;
        for (int q4 = blockIdx.x * P1_THREADS + tid; q4 < N_NODES * DCH / 4;
             q4 += nthreads) {
            float4 v = ((const float4*)x)[q4];
            ushort4 o;
            o.x = f2b(fmaxf(v.x, 0.0f) + EPS);
            o.y = f2b(fmaxf(v.y, 0.0f) + EPS);
            o.z = f2b(fmaxf(v.z, 0.0f) + EPS);
            o.w = f2b(fmaxf(v.w, 0.0f) + EPS);
            ((ushort4*)msgb)[q4] = o;
        }
    }
    // --- fused weight-frag prep (block 0, threads 0..255) ---
    if (blockIdx.x == 0 && tid < 256) {
        {   // W1 [32,64]: col-tile f
            int f = tid >> 6, lane = tid & 63;
            int col = lane & 15, quad = lane >> 4;
#pragma unroll
            for (int j = 0; j < 8; ++j) {
                int k = quad * 8 + j;
                W1f[(f * 64 + lane) * 8 + j] = f2b(W1[k * HCH + f * 16 + col]);
            }
        }
        {   // W2 [64,32]: n = col tile, kk = k half
            int n = tid >> 7, kk = (tid >> 6) & 1, lane = tid & 63;
            int col = lane & 15, quad = lane >> 4;
#pragma unroll
            for (int j = 0; j < 8; ++j) {
                int k = kk * 32 + quad * 8 + j;
                W2f[((n * 2 + kk) * 64 + lane) * 8 + j] = f2b(W2[k * DCH + n * 16 + col]);
            }
        }
    }

    const int start = blockIdx.x * CHUNK;
    const int end = min(start + CHUNK, N_EDGES);

    hcnt[tid] = 0;
    __syncthreads();

    // histogram of coarse bucket ids
    for (int i = start + tid; i < end; i += P1_THREADS)
        atomicAdd(&hcnt[eidx[i] >> 8], 1);
    __syncthreads();

    // reserve global space per bucket; cursor = global base within region
    if (tid < NB) {
        int c = hcnt[tid];
        hcur[tid] = (c > 0) ? atomicAdd(&gcnt[tid * GSTRIDE], c) : 0;
    }
    __syncthreads();

    // direct scatter: ~8-entry runs per (block,bucket); L2 merges writebacks
    for (int i = start + tid; i < end; i += P1_THREADS) {
        int dst = eidx[i];
        int src = eidx[N_EDGES + i];
        int b = dst >> 8;
        int p = atomicAdd(&hcur[b], 1);
        if (p < CAPB)
            buf[(unsigned)b * CAPB + (unsigned)p] =
                (unsigned)src | ((unsigned)(dst & (NPB - 1)) << 17);
    }
}

// ---------------------------------------------------------------------------
// Pass 2: block = quarter of a coarse bucket (64 nodes). Filtered scatter
// into 48-slot per-node LDS bins, register gather/exp/reduce, bf16 h tile
// in LDS (unioned over the dead bins region), MFMA MLP, store.
// Grid = 4*NB = 1564; LDS 17.7KB -> 8 blocks/CU, all blocks co-resident.
// ---------------------------------------------------------------------------
__global__ __launch_bounds__(256, 8) void genconv_agg_mlp(
    const unsigned short* __restrict__ msgb,
    const int* __restrict__ gcnt,
    const unsigned* __restrict__ buf,
    const float* __restrict__ beta,
    const unsigned short* __restrict__ W1f,
    const unsigned short* __restrict__ W2f,
    const float* __restrict__ b1,
    const float* __restrict__ b2,
    float* __restrict__ out)          // [N,32]
{
    // bins (12288B, phase A: scatter+gather) unions with hid (9216B,
    // phase B: MFMA). Separated by the __syncthreads() after the gather.
    __shared__ __attribute__((aligned(16))) unsigned char pool[64 * SLOT * 4];
    unsigned* bins = (unsigned*)pool;                          // [64*SLOT]
    unsigned short* hid = (unsigned short*)pool;               // [4*16*72]
    __shared__ int hcnt[64];
    __shared__ __attribute__((aligned(16))) unsigned short sha[64 * 40];  // 5 KB

    if (threadIdx.x < 64) hcnt[threadIdx.x] = 0;
    __syncthreads();

    const int cb = blockIdx.x >> 2;            // coarse bucket 0..390
    const unsigned q = blockIdx.x & 3u;        // 64-node quarter
    const int cnt = min(gcnt[cb * GSTRIDE], CAPB);
    const unsigned* bp = buf + (size_t)cb * CAPB;

    // filtered single-pass scatter into per-node bins
    {
        int nv = cnt & ~3;
        for (int i = threadIdx.x * 4; i < nv; i += 1024) {
            uint4 e4 = *(const uint4*)(bp + i);
#pragma unroll
            for (int u = 0; u < 4; ++u) {
                unsigned e = (u == 0) ? e4.x : (u == 1) ? e4.y : (u == 2) ? e4.z : e4.w;
                if (((e >> 23) & 3u) == q) {
                    int ln = (e >> 17) & 63;
                    int p = atomicAdd(&hcnt[ln], 1);
                    if (p < SLOT) bins[ln * SLOT + p] = e;
                }
            }
        }
        for (int i = nv + threadIdx.x; i < cnt; i += 256) {
            unsigned e = bp[i];
            if (((e >> 23) & 3u) == q) {
                int ln = (e >> 17) & 63;
                int p = atomicAdd(&hcnt[ln], 1);
                if (p < SLOT) bins[ln * SLOT + p] = e;
            }
        }
    }
    __syncthreads();

    const int lane32 = threadIdx.x & 31;  // channel
    const int hw = threadIdx.x >> 5;      // half-wave 0..7
    const float beta0 = beta[0];

#pragma unroll
    for (int k = 0; k < 8; ++k) {
        int ln = hw * 8 + k;
        int m = min(hcnt[ln], SLOT);
        const unsigned* bb = &bins[ln * SLOT];
        float se = 0.0f, sem = 0.0f;
        int j = 0;
        for (; j + 4 <= m; j += 4) {
            uint4 e = *(const uint4*)(bb + j);          // one ds_read_b128
            unsigned short u0 = msgb[(e.x & 0x1FFFFu) * DCH + lane32];
            unsigned short u1 = msgb[(e.y & 0x1FFFFu) * DCH + lane32];
            unsigned short u2 = msgb[(e.z & 0x1FFFFu) * DCH + lane32];
            unsigned short u3 = msgb[(e.w & 0x1FFFFu) * DCH + lane32];
            float m0 = __uint_as_float((unsigned)u0 << 16);
            float m1 = __uint_as_float((unsigned)u1 << 16);
            float m2 = __uint_as_float((unsigned)u2 << 16);
            float m3 = __uint_as_float((unsigned)u3 << 16);
            float w0 = __expf(beta0 * m0);
            float w1 = __expf(beta0 * m1);
            float w2 = __expf(beta0 * m2);
            float w3 = __expf(beta0 * m3);
            se += w0 + w1 + w2 + w3;
            sem += w0 * m0 + w1 * m1 + w2 * m2 + w3 * m3;
        }
        for (; j < m; ++j) {
            unsigned e = bb[j];
            unsigned short u = msgb[(e & 0x1FFFFu) * DCH + lane32];
            float mm = __uint_as_float((unsigned)u << 16);
            float w = __expf(beta0 * mm);
            se += w;
            sem += w * mm;
        }
        float h = (se > 0.0f) ? (sem / se) : 0.0f;
        sha[ln * 40 + lane32] = f2b(h);                 // bf16 A-tile row
    }
    __syncthreads();   // bins dead from here; pool reused as hid

    // ---- MFMA MLP: wave wv owns nodes [blockIdx.x*64 + wv*16, +16) ----
    const int wv = threadIdx.x >> 6;
    const int lane = threadIdx.x & 63;
    const int col = lane & 15, quad = lane >> 4;
    const int n0 = blockIdx.x * 64 + wv * 16;

    bf16x8 a = *(const bf16x8*)&sha[(wv * 16 + col) * 40 + quad * 8];

    const bf16x8* w1p = (const bf16x8*)W1f;
    f32x4 z = {0.f, 0.f, 0.f, 0.f};
    f32x4 c0 = __builtin_amdgcn_mfma_f32_16x16x32_bf16(a, w1p[0 * 64 + lane], z, 0, 0, 0);
    f32x4 c1 = __builtin_amdgcn_mfma_f32_16x16x32_bf16(a, w1p[1 * 64 + lane], z, 0, 0, 0);
    f32x4 c2 = __builtin_amdgcn_mfma_f32_16x16x32_bf16(a, w1p[2 * 64 + lane], z, 0, 0, 0);
    f32x4 c3 = __builtin_amdgcn_mfma_f32_16x16x32_bf16(a, w1p[3 * 64 + lane], z, 0, 0, 0);

    float bb0 = b1[col], bb1 = b1[16 + col], bb2 = b1[32 + col], bb3 = b1[48 + col];
    unsigned short* hrow = &hid[wv * 16 * 72];
#pragma unroll
    for (int r = 0; r < 4; ++r) {
        int row = quad * 4 + r;
        hrow[row * 72 + col]      = f2b(fmaxf(c0[r] + bb0, 0.f));
        hrow[row * 72 + 16 + col] = f2b(fmaxf(c1[r] + bb1, 0.f));
        hrow[row * 72 + 32 + col] = f2b(fmaxf(c2[r] + bb2, 0.f));
        hrow[row * 72 + 48 + col] = f2b(fmaxf(c3[r] + bb3, 0.f));
    }
    // per-wave LDS region: in-wave ordering suffices (r7-r11 precedent)

    bf16x8 h0 = *(const bf16x8*)&hrow[col * 72 + quad * 8];        // k 0..31
    bf16x8 h1 = *(const bf16x8*)&hrow[col * 72 + 32 + quad * 8];   // k 32..63

    const bf16x8* w2p = (const bf16x8*)W2f;
    f32x4 o0 = __builtin_amdgcn_mfma_f32_16x16x32_bf16(h0, w2p[0 * 64 + lane], z, 0, 0, 0);
    o0 = __builtin_amdgcn_mfma_f32_16x16x32_bf16(h1, w2p[1 * 64 + lane], o0, 0, 0, 0);
    f32x4 o1 = __builtin_amdgcn_mfma_f32_16x16x32_bf16(h0, w2p[2 * 64 + lane], z, 0, 0, 0);
    o1 = __builtin_amdgcn_mfma_f32_16x16x32_bf16(h1, w2p[3 * 64 + lane], o1, 0, 0, 0);

    float d0 = b2[col], d1 = b2[16 + col];
#pragma unroll
    for (int r = 0; r < 4; ++r) {
        int row = n0 + quad * 4 + r;
        if (row < N_NODES) {
            out[(size_t)row * DCH + col]      = o0[r] + d0;
            out[(size_t)row * DCH + 16 + col] = o1[r] + d1;
        }
    }
}

extern "C" void kernel_launch(void* const* d_in, const int* in_sizes, int n_in,
                              void* d_out, int out_size, void* d_ws, size_t ws_size,
                              hipStream_t stream) {
    const float* x    = (const float*)d_in[0];
    const int*   eidx = (const int*)d_in[1];
    const float* beta = (const float*)d_in[2];
    const float* W1   = (const float*)d_in[3];
    const float* b1   = (const float*)d_in[4];
    const float* W2   = (const float*)d_in[5];
    const float* b2   = (const float*)d_in[6];
    float* out = (float*)d_out;

    int* gcnt = (int*)d_ws;                                        // 25 KB
    unsigned* buf = (unsigned*)(gcnt + NB * GSTRIDE);              // 7.1 MB
    unsigned short* msgb = (unsigned short*)(buf + (size_t)NB * CAPB); // 6.4 MB
    unsigned short* W1f = msgb + (size_t)N_NODES * DCH;            // 4 KB
    unsigned short* W2f = W1f + 4 * 64 * 8;                        // 4 KB

    hipMemsetAsync(gcnt, 0, (size_t)NB * GSTRIDE * sizeof(int), stream);

    genconv_partition<<<P1_BLOCKS, P1_THREADS, 0, stream>>>(
        x, eidx, W1, W2, gcnt, buf, msgb, W1f, W2f);
    genconv_agg_mlp<<<4 * NB, 256, 0, stream>>>(msgb, gcnt, buf, beta,
                                                W1f, W2f, b1, b2, out);
}

// Round 2
// 141.026 us; speedup vs baseline: 1.1161x; 1.0112x over previous
//
#include <hip/hip_runtime.h>

// GENConv softmax-aggregation + MLP for MI355X (gfx950) — round 13.
//
// R12 post-mortem: occupancy fix landed (agg no longer in top-5; fills at
// ~45us lead). Residual arithmetic: 142.6 = agg(~35-40) + partition(~10)
// + TWO 268MB harness poison fills (~90us, at 74% HBM peak = their own
// roofline) + memset. Controllable budget ~50us, agg-dominated.
// R13: agg gather is VALU-issue-bound (~11 VALU/edge-lane, 5 of them
// address/format bookkeeping). Cut: (a) partition stores PRE-SCALED byte
// offsets: e = (src<<6)|(local<<24), so gather addr = saddr(msgb) +
// (e&0xFFFFFF) + lane*2 -> v_and+v_add into 32b voffset vs and+shl+64b-add
// chain; (b) exp2 form with beta*log2e hoisted: one v_exp_f32 via
// __builtin_amdgcn_exp2f vs __expf's mul+mul+exp. 11 -> 7 VALU/edge-lane.
//
// Math (passed r1-r12): msg = bf16(relu(x)+eps) bounded -> skip segment-max;
//   h[n,c] = sum exp(b*m)*m / sum exp(b*m);  out = relu(h@W1+b1)@W2+b2

#define N_NODES 100000
#define N_EDGES 1600000
#define DCH 32
#define HCH 64
#define EPS 1e-7f

#define NPB 256                       // nodes per coarse bucket (dst >> 8)
#define NB 391                        // ceil(100000/256)
#define CAPB 4544                     // mean 4092, +7 sigma
#define GSTRIDE 16
#define P1_BLOCKS 512
#define P1_THREADS 512
#define CHUNK 3125                    // 512 * 3125 = 1.6M exactly
#define SLOT 48                       // per-node LDS bin cap (P[Poi16>48]~1e-11)

typedef __attribute__((ext_vector_type(8))) short bf16x8;
typedef __attribute__((ext_vector_type(4))) float f32x4;

__device__ inline unsigned short f2b(float v) {   // fp32 -> bf16 RNE
    unsigned u = __float_as_uint(v);
    return (unsigned short)((u + 0x7FFFu + ((u >> 16) & 1u)) >> 16);
}

// ---------------------------------------------------------------------------
// Pass 1: bf16 msg table + weight frags + coarse-bucket partition via
// DIRECT scatter (no sort, no flush). LDS = 4 KB -> 32 waves/CU.
// Entry packing (R13): bits 0-23 = src*64 (byte offset of msg row, bit 23
// always 0), bits 24-31 = dst&255 (local node; bits 30-31 = quarter).
// ---------------------------------------------------------------------------
__global__ __launch_bounds__(P1_THREADS) void genconv_partition(
    const float* __restrict__ x,
    const int* __restrict__ eidx,     // [2E]: [0,E)=dst, [E,2E)=src
    const float* __restrict__ W1, const float* __restrict__ W2,
    int* __restrict__ gcnt,           // [NB*GSTRIDE] zeroed; bucket totals
    unsigned* __restrict__ buf,       // [NB*CAPB] packed entries
    unsigned short* __restrict__ msgb,
    unsigned short* __restrict__ W1f, unsigned short* __restrict__ W2f)
{
    __shared__ int hcnt[512];
    __shared__ int hcur[512];

    const int tid = threadIdx.x;

    // --- fused bf16 msg table: grid-stride float4 over x (800k float4) ---
    {
        const int nthreads = P1_BLOCKS * P1_THREADS;
        for (int q4 = blockIdx.x * P1_THREADS + tid; q4 < N_NODES * DCH / 4;
             q4 += nthreads) {
            float4 v = ((const float4*)x)[q4];
            ushort4 o;
            o.x = f2b(fmaxf(v.x, 0.0f) + EPS);
            o.y = f2b(fmaxf(v.y, 0.0f) + EPS);
            o.z = f2b(fmaxf(v.z, 0.0f) + EPS);
            o.w = f2b(fmaxf(v.w, 0.0f) + EPS);
            ((ushort4*)msgb)[q4] = o;
        }
    }
    // --- fused weight-frag prep (block 0, threads 0..255) ---
    if (blockIdx.x == 0 && tid < 256) {
        {   // W1 [32,64]: col-tile f
            int f = tid >> 6, lane = tid & 63;
            int col = lane & 15, quad = lane >> 4;
#pragma unroll
            for (int j = 0; j < 8; ++j) {
                int k = quad * 8 + j;
                W1f[(f * 64 + lane) * 8 + j] = f2b(W1[k * HCH + f * 16 + col]);
            }
        }
        {   // W2 [64,32]: n = col tile, kk = k half
            int n = tid >> 7, kk = (tid >> 6) & 1, lane = tid & 63;
            int col = lane & 15, quad = lane >> 4;
#pragma unroll
            for (int j = 0; j < 8; ++j) {
                int k = kk * 32 + quad * 8 + j;
                W2f[((n * 2 + kk) * 64 + lane) * 8 + j] = f2b(W2[k * DCH + n * 16 + col]);
            }
        }
    }

    const int start = blockIdx.x * CHUNK;
    const int end = min(start + CHUNK, N_EDGES);

    hcnt[tid] = 0;
    __syncthreads();

    // histogram of coarse bucket ids
    for (int i = start + tid; i < end; i += P1_THREADS)
        atomicAdd(&hcnt[eidx[i] >> 8], 1);
    __syncthreads();

    // reserve global space per bucket; cursor = global base within region
    if (tid < NB) {
        int c = hcnt[tid];
        hcur[tid] = (c > 0) ? atomicAdd(&gcnt[tid * GSTRIDE], c) : 0;
    }
    __syncthreads();

    // direct scatter: ~8-entry runs per (block,bucket); L2 merges writebacks
    for (int i = start + tid; i < end; i += P1_THREADS) {
        int dst = eidx[i];
        int src = eidx[N_EDGES + i];
        int b = dst >> 8;
        int p = atomicAdd(&hcur[b], 1);
        if (p < CAPB)
            buf[(unsigned)b * CAPB + (unsigned)p] =
                ((unsigned)src << 6) | ((unsigned)(dst & (NPB - 1)) << 24);
    }
}

// ---------------------------------------------------------------------------
// Pass 2: block = quarter of a coarse bucket (64 nodes). Filtered scatter
// into 48-slot per-node LDS bins, register gather/exp/reduce, bf16 h tile
// in LDS (unioned over the dead bins region), MFMA MLP, store.
// Grid = 4*NB = 1564; LDS 17.7KB -> 8 blocks/CU, all blocks co-resident.
// ---------------------------------------------------------------------------
__global__ __launch_bounds__(256, 8) void genconv_agg_mlp(
    const unsigned short* __restrict__ msgb,
    const int* __restrict__ gcnt,
    const unsigned* __restrict__ buf,
    const float* __restrict__ beta,
    const unsigned short* __restrict__ W1f,
    const unsigned short* __restrict__ W2f,
    const float* __restrict__ b1,
    const float* __restrict__ b2,
    float* __restrict__ out)          // [N,32]
{
    // bins (12288B, phase A: scatter+gather) unions with hid (9216B,
    // phase B: MFMA). Separated by the __syncthreads() after the gather.
    __shared__ __attribute__((aligned(16))) unsigned char pool[64 * SLOT * 4];
    unsigned* bins = (unsigned*)pool;                          // [64*SLOT]
    unsigned short* hid = (unsigned short*)pool;               // [4*16*72]
    __shared__ int hcnt[64];
    __shared__ __attribute__((aligned(16))) unsigned short sha[64 * 40];  // 5 KB

    if (threadIdx.x < 64) hcnt[threadIdx.x] = 0;
    __syncthreads();

    const int cb = blockIdx.x >> 2;            // coarse bucket 0..390
    const unsigned q = blockIdx.x & 3u;        // 64-node quarter
    const int cnt = min(gcnt[cb * GSTRIDE], CAPB);
    const unsigned* bp = buf + (size_t)cb * CAPB;

    // filtered single-pass scatter into per-node bins
    {
        int nv = cnt & ~3;
        for (int i = threadIdx.x * 4; i < nv; i += 1024) {
            uint4 e4 = *(const uint4*)(bp + i);
#pragma unroll
            for (int u = 0; u < 4; ++u) {
                unsigned e = (u == 0) ? e4.x : (u == 1) ? e4.y : (u == 2) ? e4.z : e4.w;
                if ((e >> 30) == q) {
                    int ln = (e >> 24) & 63;
                    int p = atomicAdd(&hcnt[ln], 1);
                    if (p < SLOT) bins[ln * SLOT + p] = e;
                }
            }
        }
        for (int i = nv + threadIdx.x; i < cnt; i += 256) {
            unsigned e = bp[i];
            if ((e >> 30) == q) {
                int ln = (e >> 24) & 63;
                int p = atomicAdd(&hcnt[ln], 1);
                if (p < SLOT) bins[ln * SLOT + p] = e;
            }
        }
    }
    __syncthreads();

    const int lane32 = threadIdx.x & 31;  // channel
    const int hw = threadIdx.x >> 5;      // half-wave 0..7
    const float bl2 = beta[0] * 1.4426950408889634f;   // beta * log2(e)
    const unsigned loff = (unsigned)lane32 * 2u;       // channel byte offset
    const char* mb = (const char*)msgb;                // saddr base

#pragma unroll
    for (int k = 0; k < 8; ++k) {
        int ln = hw * 8 + k;
        int m = min(hcnt[ln], SLOT);
        const unsigned* bb = &bins[ln * SLOT];
        float se = 0.0f, sem = 0.0f;
        int j = 0;
        for (; j + 4 <= m; j += 4) {
            uint4 e = *(const uint4*)(bb + j);          // one ds_read_b128
            // entry & 0xFFFFFF is the msg row's byte offset (src*64)
            unsigned short u0 = *(const unsigned short*)(mb + ((e.x & 0xFFFFFFu) + loff));
            unsigned short u1 = *(const unsigned short*)(mb + ((e.y & 0xFFFFFFu) + loff));
            unsigned short u2 = *(const unsigned short*)(mb + ((e.z & 0xFFFFFFu) + loff));
            unsigned short u3 = *(const unsigned short*)(mb + ((e.w & 0xFFFFFFu) + loff));
            float m0 = __uint_as_float((unsigned)u0 << 16);
            float m1 = __uint_as_float((unsigned)u1 << 16);
            float m2 = __uint_as_float((unsigned)u2 << 16);
            float m3 = __uint_as_float((unsigned)u3 << 16);
            float w0 = __builtin_amdgcn_exp2f(bl2 * m0);
            float w1 = __builtin_amdgcn_exp2f(bl2 * m1);
            float w2 = __builtin_amdgcn_exp2f(bl2 * m2);
            float w3 = __builtin_amdgcn_exp2f(bl2 * m3);
            se += (w0 + w1) + (w2 + w3);
            sem += w0 * m0 + w1 * m1 + w2 * m2 + w3 * m3;
        }
        for (; j < m; ++j) {
            unsigned e = bb[j];
            unsigned short u = *(const unsigned short*)(mb + ((e & 0xFFFFFFu) + loff));
            float mm = __uint_as_float((unsigned)u << 16);
            float w = __builtin_amdgcn_exp2f(bl2 * mm);
            se += w;
            sem += w * mm;
        }
        float h = (se > 0.0f) ? (sem / se) : 0.0f;
        sha[ln * 40 + lane32] = f2b(h);                 // bf16 A-tile row
    }
    __syncthreads();   // bins dead from here; pool reused as hid

    // ---- MFMA MLP: wave wv owns nodes [blockIdx.x*64 + wv*16, +16) ----
    const int wv = threadIdx.x >> 6;
    const int lane = threadIdx.x & 63;
    const int col = lane & 15, quad = lane >> 4;
    const int n0 = blockIdx.x * 64 + wv * 16;

    bf16x8 a = *(const bf16x8*)&sha[(wv * 16 + col) * 40 + quad * 8];

    const bf16x8* w1p = (const bf16x8*)W1f;
    f32x4 z = {0.f, 0.f, 0.f, 0.f};
    f32x4 c0 = __builtin_amdgcn_mfma_f32_16x16x32_bf16(a, w1p[0 * 64 + lane], z, 0, 0, 0);
    f32x4 c1 = __builtin_amdgcn_mfma_f32_16x16x32_bf16(a, w1p[1 * 64 + lane], z, 0, 0, 0);
    f32x4 c2 = __builtin_amdgcn_mfma_f32_16x16x32_bf16(a, w1p[2 * 64 + lane], z, 0, 0, 0);
    f32x4 c3 = __builtin_amdgcn_mfma_f32_16x16x32_bf16(a, w1p[3 * 64 + lane], z, 0, 0, 0);

    float bb0 = b1[col], bb1 = b1[16 + col], bb2 = b1[32 + col], bb3 = b1[48 + col];
    unsigned short* hrow = &hid[wv * 16 * 72];
#pragma unroll
    for (int r = 0; r < 4; ++r) {
        int row = quad * 4 + r;
        hrow[row * 72 + col]      = f2b(fmaxf(c0[r] + bb0, 0.f));
        hrow[row * 72 + 16 + col] = f2b(fmaxf(c1[r] + bb1, 0.f));
        hrow[row * 72 + 32 + col] = f2b(fmaxf(c2[r] + bb2, 0.f));
        hrow[row * 72 + 48 + col] = f2b(fmaxf(c3[r] + bb3, 0.f));
    }
    // per-wave LDS region: in-wave ordering suffices (r7-r12 precedent)

    bf16x8 h0 = *(const bf16x8*)&hrow[col * 72 + quad * 8];        // k 0..31
    bf16x8 h1 = *(const bf16x8*)&hrow[col * 72 + 32 + quad * 8];   // k 32..63

    const bf16x8* w2p = (const bf16x8*)W2f;
    f32x4 o0 = __builtin_amdgcn_mfma_f32_16x16x32_bf16(h0, w2p[0 * 64 + lane], z, 0, 0, 0);
    o0 = __builtin_amdgcn_mfma_f32_16x16x32_bf16(h1, w2p[1 * 64 + lane], o0, 0, 0, 0);
    f32x4 o1 = __builtin_amdgcn_mfma_f32_16x16x32_bf16(h0, w2p[2 * 64 + lane], z, 0, 0, 0);
    o1 = __builtin_amdgcn_mfma_f32_16x16x32_bf16(h1, w2p[3 * 64 + lane], o1, 0, 0, 0);

    float d0 = b2[col], d1 = b2[16 + col];
#pragma unroll
    for (int r = 0; r < 4; ++r) {
        int row = n0 + quad * 4 + r;
        if (row < N_NODES) {
            out[(size_t)row * DCH + col]      = o0[r] + d0;
            out[(size_t)row * DCH + 16 + col] = o1[r] + d1;
        }
    }
}

extern "C" void kernel_launch(void* const* d_in, const int* in_sizes, int n_in,
                              void* d_out, int out_size, void* d_ws, size_t ws_size,
                              hipStream_t stream) {
    const float* x    = (const float*)d_in[0];
    const int*   eidx = (const int*)d_in[1];
    const float* beta = (const float*)d_in[2];
    const float* W1   = (const float*)d_in[3];
    const float* b1   = (const float*)d_in[4];
    const float* W2   = (const float*)d_in[5];
    const float* b2   = (const float*)d_in[6];
    float* out = (float*)d_out;

    int* gcnt = (int*)d_ws;                                        // 25 KB
    unsigned* buf = (unsigned*)(gcnt + NB * GSTRIDE);              // 7.1 MB
    unsigned short* msgb = (unsigned short*)(buf + (size_t)NB * CAPB); // 6.4 MB
    unsigned short* W1f = msgb + (size_t)N_NODES * DCH;            // 4 KB
    unsigned short* W2f = W1f + 4 * 64 * 8;                        // 4 KB

    hipMemsetAsync(gcnt, 0, (size_t)NB * GSTRIDE * sizeof(int), stream);

    genconv_partition<<<P1_BLOCKS, P1_THREADS, 0, stream>>>(
        x, eidx, W1, W2, gcnt, buf, msgb, W1f, W2f);
    genconv_agg_mlp<<<4 * NB, 256, 0, stream>>>(msgb, gcnt, buf, beta,
                                                W1f, W2f, b1, b2, out);
}

// Round 3
// 136.000 us; speedup vs baseline: 1.1573x; 1.0370x over previous
//
#include <hip/hip_runtime.h>

// GENConv softmax-aggregation + MLP for MI355X (gfx950) — round 14.
//
// R13 post-mortem: op-count cut gave only -1.6us; calibration says the whole
// exp/fma math chain is ~10us of agg's ~40us. agg is LATENCY-bound in the
// gather: 4 loads in flight per half-wave, serial nodes (runtime trips
// block pipelining; VGPR=40 = shallow pipeline), divergent tails.
// R14: branchless dual-node gather. bins pre-filled with a SENTINEL offset
// to an extra msgb row = 0xFF7F (-3.4e38): w=exp2(-inf)=+0, w*m=+0 -> pad
// entries contribute exactly 0 to se/sem. Per node-pair: T=max(ceil/4)
// iterations, 8 independent loads in flight, no tail loop. Scatter writes
// PRE-MASKED entries (e&0xFFFFFF): v_and moves from per-ch-edge to
// per-entry (~1.5us by R13 calibration).
//
// Math (passed r1-r13): msg = bf16(relu(x)+eps) bounded -> skip segment-max;
//   h[n,c] = sum exp(b*m)*m / sum exp(b*m);  out = relu(h@W1+b1)@W2+b2

#define N_NODES 100000
#define N_EDGES 1600000
#define DCH 32
#define HCH 64
#define EPS 1e-7f

#define NPB 256                       // nodes per coarse bucket (dst >> 8)
#define NB 391                        // ceil(100000/256)
#define CAPB 4544                     // mean 4092, +7 sigma
#define GSTRIDE 16
#define P1_BLOCKS 512
#define P1_THREADS 512
#define CHUNK 3125                    // 512 * 3125 = 1.6M exactly
#define SLOT 48                       // per-node LDS bin cap (P[Poi16>48]~1e-11)
#define SENT_OFF (N_NODES * 64u)      // byte offset of sentinel msg row

typedef __attribute__((ext_vector_type(8))) short bf16x8;
typedef __attribute__((ext_vector_type(4))) float f32x4;

__device__ inline unsigned short f2b(float v) {   // fp32 -> bf16 RNE
    unsigned u = __float_as_uint(v);
    return (unsigned short)((u + 0x7FFFu + ((u >> 16) & 1u)) >> 16);
}

// ---------------------------------------------------------------------------
// Pass 1: bf16 msg table (+ sentinel row) + weight frags + coarse-bucket
// partition via DIRECT scatter. LDS = 4 KB -> 32 waves/CU.
// Entry packing: bits 0-23 = src*64 (byte offset of msg row), bits 24-31 =
// dst&255 (local node; bits 30-31 = quarter).
// ---------------------------------------------------------------------------
__global__ __launch_bounds__(P1_THREADS) void genconv_partition(
    const float* __restrict__ x,
    const int* __restrict__ eidx,     // [2E]: [0,E)=dst, [E,2E)=src
    const float* __restrict__ W1, const float* __restrict__ W2,
    int* __restrict__ gcnt,           // [NB*GSTRIDE] zeroed; bucket totals
    unsigned* __restrict__ buf,       // [NB*CAPB] packed entries
    unsigned short* __restrict__ msgb,
    unsigned short* __restrict__ W1f, unsigned short* __restrict__ W2f)
{
    __shared__ int hcnt[512];
    __shared__ int hcur[512];

    const int tid = threadIdx.x;

    // --- fused bf16 msg table: grid-stride float4 over x (800k float4) ---
    {
        const int nthreads = P1_BLOCKS * P1_THREADS;
        for (int q4 = blockIdx.x * P1_THREADS + tid; q4 < N_NODES * DCH / 4;
             q4 += nthreads) {
            float4 v = ((const float4*)x)[q4];
            ushort4 o;
            o.x = f2b(fmaxf(v.x, 0.0f) + EPS);
            o.y = f2b(fmaxf(v.y, 0.0f) + EPS);
            o.z = f2b(fmaxf(v.z, 0.0f) + EPS);
            o.w = f2b(fmaxf(v.w, 0.0f) + EPS);
            ((ushort4*)msgb)[q4] = o;
        }
    }
    // --- fused weight-frag prep + sentinel row (block 0) ---
    if (blockIdx.x == 0 && tid < 256) {
        {   // W1 [32,64]: col-tile f
            int f = tid >> 6, lane = tid & 63;
            int col = lane & 15, quad = lane >> 4;
#pragma unroll
            for (int j = 0; j < 8; ++j) {
                int k = quad * 8 + j;
                W1f[(f * 64 + lane) * 8 + j] = f2b(W1[k * HCH + f * 16 + col]);
            }
        }
        {   // W2 [64,32]: n = col tile, kk = k half
            int n = tid >> 7, kk = (tid >> 6) & 1, lane = tid & 63;
            int col = lane & 15, quad = lane >> 4;
#pragma unroll
            for (int j = 0; j < 8; ++j) {
                int k = kk * 32 + quad * 8 + j;
                W2f[((n * 2 + kk) * 64 + lane) * 8 + j] = f2b(W2[k * DCH + n * 16 + col]);
            }
        }
        // sentinel msg row: m = -3.39e38 -> w = exp2(-inf) = +0, w*m = +-0
        if (tid < DCH) msgb[N_NODES * DCH + tid] = 0xFF7Fu;
    }

    const int start = blockIdx.x * CHUNK;
    const int end = min(start + CHUNK, N_EDGES);

    hcnt[tid] = 0;
    __syncthreads();

    // histogram of coarse bucket ids
    for (int i = start + tid; i < end; i += P1_THREADS)
        atomicAdd(&hcnt[eidx[i] >> 8], 1);
    __syncthreads();

    // reserve global space per bucket; cursor = global base within region
    if (tid < NB) {
        int c = hcnt[tid];
        hcur[tid] = (c > 0) ? atomicAdd(&gcnt[tid * GSTRIDE], c) : 0;
    }
    __syncthreads();

    // direct scatter: ~8-entry runs per (block,bucket); L2 merges writebacks
    for (int i = start + tid; i < end; i += P1_THREADS) {
        int dst = eidx[i];
        int src = eidx[N_EDGES + i];
        int b = dst >> 8;
        int p = atomicAdd(&hcur[b], 1);
        if (p < CAPB)
            buf[(unsigned)b * CAPB + (unsigned)p] =
                ((unsigned)src << 6) | ((unsigned)(dst & (NPB - 1)) << 24);
    }
}

// ---------------------------------------------------------------------------
// Pass 2: block = quarter of a coarse bucket (64 nodes). Filtered scatter
// into sentinel-padded 48-slot per-node LDS bins, branchless dual-node
// register gather (8 loads in flight), bf16 h tile in LDS (unioned over the
// dead bins region), MFMA MLP, store.
// Grid = 4*NB = 1564; LDS 17.7KB -> 8 blocks/CU, all blocks co-resident.
// ---------------------------------------------------------------------------
__global__ __launch_bounds__(256, 8) void genconv_agg_mlp(
    const unsigned short* __restrict__ msgb,
    const int* __restrict__ gcnt,
    const unsigned* __restrict__ buf,
    const float* __restrict__ beta,
    const unsigned short* __restrict__ W1f,
    const unsigned short* __restrict__ W2f,
    const float* __restrict__ b1,
    const float* __restrict__ b2,
    float* __restrict__ out)          // [N,32]
{
    // bins (12288B, phase A: scatter+gather) unions with hid (9216B,
    // phase B: MFMA). Separated by the __syncthreads() after the gather.
    __shared__ __attribute__((aligned(16))) unsigned char pool[64 * SLOT * 4];
    unsigned* bins = (unsigned*)pool;                          // [64*SLOT]
    unsigned short* hid = (unsigned short*)pool;               // [4*16*72]
    __shared__ int hcnt[64];
    __shared__ __attribute__((aligned(16))) unsigned short sha[64 * 40];  // 5 KB

    // pre-fill bins with sentinel so over-read pads contribute exactly 0
    {
        uint4 sv = {SENT_OFF, SENT_OFF, SENT_OFF, SENT_OFF};
        for (int i = threadIdx.x; i < 64 * SLOT / 4; i += 256)
            ((uint4*)bins)[i] = sv;
        if (threadIdx.x < 64) hcnt[threadIdx.x] = 0;
    }
    __syncthreads();

    const int cb = blockIdx.x >> 2;            // coarse bucket 0..390
    const unsigned q = blockIdx.x & 3u;        // 64-node quarter
    const int cnt = min(gcnt[cb * GSTRIDE], CAPB);
    const unsigned* bp = buf + (size_t)cb * CAPB;

    // filtered single-pass scatter into per-node bins (pre-masked entries)
    {
        int nv = cnt & ~3;
        for (int i = threadIdx.x * 4; i < nv; i += 1024) {
            uint4 e4 = *(const uint4*)(bp + i);
#pragma unroll
            for (int u = 0; u < 4; ++u) {
                unsigned e = (u == 0) ? e4.x : (u == 1) ? e4.y : (u == 2) ? e4.z : e4.w;
                if ((e >> 30) == q) {
                    int ln = (e >> 24) & 63;
                    int p = atomicAdd(&hcnt[ln], 1);
                    if (p < SLOT) bins[ln * SLOT + p] = e & 0xFFFFFFu;
                }
            }
        }
        for (int i = nv + threadIdx.x; i < cnt; i += 256) {
            unsigned e = bp[i];
            if ((e >> 30) == q) {
                int ln = (e >> 24) & 63;
                int p = atomicAdd(&hcnt[ln], 1);
                if (p < SLOT) bins[ln * SLOT + p] = e & 0xFFFFFFu;
            }
        }
    }
    __syncthreads();

    const int lane32 = threadIdx.x & 31;  // channel
    const int hw = threadIdx.x >> 5;      // half-wave 0..7
    const float bl2 = beta[0] * 1.4426950408889634f;   // beta * log2(e)
    const unsigned loff = (unsigned)lane32 * 2u;       // channel byte offset
    const char* mb = (const char*)msgb;                // saddr base

    // branchless dual-node gather: 2 entry streams, 8 loads in flight
#pragma unroll
    for (int kp = 0; kp < 4; ++kp) {
        int ln = hw * 8 + kp * 2;
        int ma = min(hcnt[ln], SLOT);
        int mc = min(hcnt[ln + 1], SLOT);
        int T = max((ma + 3) >> 2, (mc + 3) >> 2);
        const uint4* ba = (const uint4*)&bins[ln * SLOT];
        const uint4* bc = (const uint4*)&bins[(ln + 1) * SLOT];
        float sea = 0.0f, sma = 0.0f, sec = 0.0f, smc = 0.0f;
        for (int t = 0; t < T; ++t) {
            uint4 ea = ba[t];
            uint4 ec = bc[t];
            unsigned short a0 = *(const unsigned short*)(mb + (ea.x + loff));
            unsigned short a1 = *(const unsigned short*)(mb + (ea.y + loff));
            unsigned short a2 = *(const unsigned short*)(mb + (ea.z + loff));
            unsigned short a3 = *(const unsigned short*)(mb + (ea.w + loff));
            unsigned short c0 = *(const unsigned short*)(mb + (ec.x + loff));
            unsigned short c1 = *(const unsigned short*)(mb + (ec.y + loff));
            unsigned short c2 = *(const unsigned short*)(mb + (ec.z + loff));
            unsigned short c3 = *(const unsigned short*)(mb + (ec.w + loff));
            float ma0 = __uint_as_float((unsigned)a0 << 16);
            float ma1 = __uint_as_float((unsigned)a1 << 16);
            float ma2 = __uint_as_float((unsigned)a2 << 16);
            float ma3 = __uint_as_float((unsigned)a3 << 16);
            float mc0 = __uint_as_float((unsigned)c0 << 16);
            float mc1 = __uint_as_float((unsigned)c1 << 16);
            float mc2 = __uint_as_float((unsigned)c2 << 16);
            float mc3 = __uint_as_float((unsigned)c3 << 16);
            float wa0 = __builtin_amdgcn_exp2f(bl2 * ma0);
            float wa1 = __builtin_amdgcn_exp2f(bl2 * ma1);
            float wa2 = __builtin_amdgcn_exp2f(bl2 * ma2);
            float wa3 = __builtin_amdgcn_exp2f(bl2 * ma3);
            float wc0 = __builtin_amdgcn_exp2f(bl2 * mc0);
            float wc1 = __builtin_amdgcn_exp2f(bl2 * mc1);
            float wc2 = __builtin_amdgcn_exp2f(bl2 * mc2);
            float wc3 = __builtin_amdgcn_exp2f(bl2 * mc3);
            sea += (wa0 + wa1) + (wa2 + wa3);
            sec += (wc0 + wc1) + (wc2 + wc3);
            sma += wa0 * ma0 + wa1 * ma1 + wa2 * ma2 + wa3 * ma3;
            smc += wc0 * mc0 + wc1 * mc1 + wc2 * mc2 + wc3 * mc3;
        }
        float ha = (sea > 0.0f) ? (sma / sea) : 0.0f;
        float hc = (sec > 0.0f) ? (smc / sec) : 0.0f;
        sha[ln * 40 + lane32] = f2b(ha);
        sha[(ln + 1) * 40 + lane32] = f2b(hc);
    }
    __syncthreads();   // bins dead from here; pool reused as hid

    // ---- MFMA MLP: wave wv owns nodes [blockIdx.x*64 + wv*16, +16) ----
    const int wv = threadIdx.x >> 6;
    const int lane = threadIdx.x & 63;
    const int col = lane & 15, quad = lane >> 4;
    const int n0 = blockIdx.x * 64 + wv * 16;

    bf16x8 a = *(const bf16x8*)&sha[(wv * 16 + col) * 40 + quad * 8];

    const bf16x8* w1p = (const bf16x8*)W1f;
    f32x4 z = {0.f, 0.f, 0.f, 0.f};
    f32x4 c0 = __builtin_amdgcn_mfma_f32_16x16x32_bf16(a, w1p[0 * 64 + lane], z, 0, 0, 0);
    f32x4 c1 = __builtin_amdgcn_mfma_f32_16x16x32_bf16(a, w1p[1 * 64 + lane], z, 0, 0, 0);
    f32x4 c2 = __builtin_amdgcn_mfma_f32_16x16x32_bf16(a, w1p[2 * 64 + lane], z, 0, 0, 0);
    f32x4 c3 = __builtin_amdgcn_mfma_f32_16x16x32_bf16(a, w1p[3 * 64 + lane], z, 0, 0, 0);

    float bb0 = b1[col], bb1 = b1[16 + col], bb2 = b1[32 + col], bb3 = b1[48 + col];
    unsigned short* hrow = &hid[wv * 16 * 72];
#pragma unroll
    for (int r = 0; r < 4; ++r) {
        int row = quad * 4 + r;
        hrow[row * 72 + col]      = f2b(fmaxf(c0[r] + bb0, 0.f));
        hrow[row * 72 + 16 + col] = f2b(fmaxf(c1[r] + bb1, 0.f));
        hrow[row * 72 + 32 + col] = f2b(fmaxf(c2[r] + bb2, 0.f));
        hrow[row * 72 + 48 + col] = f2b(fmaxf(c3[r] + bb3, 0.f));
    }
    // per-wave LDS region: in-wave ordering suffices (r7-r13 precedent)

    bf16x8 h0 = *(const bf16x8*)&hrow[col * 72 + quad * 8];        // k 0..31
    bf16x8 h1 = *(const bf16x8*)&hrow[col * 72 + 32 + quad * 8];   // k 32..63

    const bf16x8* w2p = (const bf16x8*)W2f;
    f32x4 o0 = __builtin_amdgcn_mfma_f32_16x16x32_bf16(h0, w2p[0 * 64 + lane], z, 0, 0, 0);
    o0 = __builtin_amdgcn_mfma_f32_16x16x32_bf16(h1, w2p[1 * 64 + lane], o0, 0, 0, 0);
    f32x4 o1 = __builtin_amdgcn_mfma_f32_16x16x32_bf16(h0, w2p[2 * 64 + lane], z, 0, 0, 0);
    o1 = __builtin_amdgcn_mfma_f32_16x16x32_bf16(h1, w2p[3 * 64 + lane], o1, 0, 0, 0);

    float d0 = b2[col], d1 = b2[16 + col];
#pragma unroll
    for (int r = 0; r < 4; ++r) {
        int row = n0 + quad * 4 + r;
        if (row < N_NODES) {
            out[(size_t)row * DCH + col]      = o0[r] + d0;
            out[(size_t)row * DCH + 16 + col] = o1[r] + d1;
        }
    }
}

extern "C" void kernel_launch(void* const* d_in, const int* in_sizes, int n_in,
                              void* d_out, int out_size, void* d_ws, size_t ws_size,
                              hipStream_t stream) {
    const float* x    = (const float*)d_in[0];
    const int*   eidx = (const int*)d_in[1];
    const float* beta = (const float*)d_in[2];
    const float* W1   = (const float*)d_in[3];
    const float* b1   = (const float*)d_in[4];
    const float* W2   = (const float*)d_in[5];
    const float* b2   = (const float*)d_in[6];
    float* out = (float*)d_out;

    int* gcnt = (int*)d_ws;                                        // 25 KB
    unsigned* buf = (unsigned*)(gcnt + NB * GSTRIDE);              // 7.1 MB
    unsigned short* msgb = (unsigned short*)(buf + (size_t)NB * CAPB); // 6.4 MB + sentinel
    unsigned short* W1f = msgb + (size_t)(N_NODES + 1) * DCH;      // 4 KB
    unsigned short* W2f = W1f + 4 * 64 * 8;                        // 4 KB

    hipMemsetAsync(gcnt, 0, (size_t)NB * GSTRIDE * sizeof(int), stream);

    genconv_partition<<<P1_BLOCKS, P1_THREADS, 0, stream>>>(
        x, eidx, W1, W2, gcnt, buf, msgb, W1f, W2f);
    genconv_agg_mlp<<<4 * NB, 256, 0, stream>>>(msgb, gcnt, buf, beta,
                                                W1f, W2f, b1, b2, out);
}

// Round 4
// 129.512 us; speedup vs baseline: 1.2153x; 1.0501x over previous
//
#include <hip/hip_runtime.h>

// GENConv softmax-aggregation + MLP for MI355X (gfx950) — round 15.
//
// R14 post-mortem: dual-stream gather -5us (matched latency theory).
// R15 theory: wave processes 4 nodes concurrently, trip = max over them of
// ceil(m/4) -> ~40% divergence/pad waste for Poisson(16); and 2B lane loads
// deliver only 1 ch-edge per VMEM instr. Fix: (a) DWORD gather — lane owns
// 2 channels, quarter-wave per node: 8 in-flight dwords = 16 ch-edges/iter
// (2x fewer iters, 2x fewer VMEM instrs/ch-edge); (b) count-balanced node
// assignment: rank 64 nodes by bin count (branch-free O(64^2) rank), snake
// rank-windows across waves so concurrent nodes have similar counts.
// Partition: cache dst chunk in LDS (12.5KB) -> eidx dst read once (-6.4MB).
//
// Math (passed r1-r14): msg = bf16(relu(x)+eps) bounded -> skip segment-max;
//   h[n,c] = sum exp(b*m)*m / sum exp(b*m);  out = relu(h@W1+b1)@W2+b2

#define N_NODES 100000
#define N_EDGES 1600000
#define DCH 32
#define HCH 64
#define EPS 1e-7f

#define NPB 256                       // nodes per coarse bucket (dst >> 8)
#define NB 391                        // ceil(100000/256)
#define CAPB 4544                     // mean 4092, +7 sigma
#define GSTRIDE 16
#define P1_BLOCKS 512
#define P1_THREADS 512
#define CHUNK 3125                    // 512 * 3125 = 1.6M exactly
#define SLOT 48                       // per-node LDS bin cap (P[Poi16>48]~1e-11)
#define SENT_OFF (N_NODES * 64u)      // byte offset of sentinel msg row

typedef __attribute__((ext_vector_type(8))) short bf16x8;
typedef __attribute__((ext_vector_type(4))) float f32x4;

__device__ inline unsigned short f2b(float v) {   // fp32 -> bf16 RNE
    unsigned u = __float_as_uint(v);
    return (unsigned short)((u + 0x7FFFu + ((u >> 16) & 1u)) >> 16);
}

// ---------------------------------------------------------------------------
// Pass 1: bf16 msg table (+ sentinel row) + weight frags + coarse-bucket
// partition via DIRECT scatter. dst chunk cached in LDS (read once).
// Entry packing: bits 0-23 = src*64 (byte offset of msg row), bits 24-31 =
// dst&255 (local node; bits 30-31 = quarter).
// ---------------------------------------------------------------------------
__global__ __launch_bounds__(P1_THREADS) void genconv_partition(
    const float* __restrict__ x,
    const int* __restrict__ eidx,     // [2E]: [0,E)=dst, [E,2E)=src
    const float* __restrict__ W1, const float* __restrict__ W2,
    int* __restrict__ gcnt,           // [NB*GSTRIDE] zeroed; bucket totals
    unsigned* __restrict__ buf,       // [NB*CAPB] packed entries
    unsigned short* __restrict__ msgb,
    unsigned short* __restrict__ W1f, unsigned short* __restrict__ W2f)
{
    __shared__ int hcnt[512];
    __shared__ int hcur[512];
    __shared__ int dstc[CHUNK];       // 12.5 KB dst cache

    const int tid = threadIdx.x;

    // --- fused bf16 msg table: grid-stride float4 over x (800k float4) ---
    {
        const int nthreads = P1_BLOCKS * P1_THREADS;
        for (int q4 = blockIdx.x * P1_THREADS + tid; q4 < N_NODES * DCH / 4;
             q4 += nthreads) {
            float4 v = ((const float4*)x)[q4];
            ushort4 o;
            o.x = f2b(fmaxf(v.x, 0.0f) + EPS);
            o.y = f2b(fmaxf(v.y, 0.0f) + EPS);
            o.z = f2b(fmaxf(v.z, 0.0f) + EPS);
            o.w = f2b(fmaxf(v.w, 0.0f) + EPS);
            ((ushort4*)msgb)[q4] = o;
        }
    }
    // --- fused weight-frag prep + sentinel row (block 0) ---
    if (blockIdx.x == 0 && tid < 256) {
        {   // W1 [32,64]: col-tile f
            int f = tid >> 6, lane = tid & 63;
            int col = lane & 15, quad = lane >> 4;
#pragma unroll
            for (int j = 0; j < 8; ++j) {
                int k = quad * 8 + j;
                W1f[(f * 64 + lane) * 8 + j] = f2b(W1[k * HCH + f * 16 + col]);
            }
        }
        {   // W2 [64,32]: n = col tile, kk = k half
            int n = tid >> 7, kk = (tid >> 6) & 1, lane = tid & 63;
            int col = lane & 15, quad = lane >> 4;
#pragma unroll
            for (int j = 0; j < 8; ++j) {
                int k = kk * 32 + quad * 8 + j;
                W2f[((n * 2 + kk) * 64 + lane) * 8 + j] = f2b(W2[k * DCH + n * 16 + col]);
            }
        }
        // sentinel msg row: m = -3.39e38 -> w = exp2(-inf) = +0, w*m = +-0
        if (tid < DCH) msgb[N_NODES * DCH + tid] = 0xFF7Fu;
    }

    const int start = blockIdx.x * CHUNK;
    const int end = min(start + CHUNK, N_EDGES);
    const int n = end - start;

    hcnt[tid] = 0;
    __syncthreads();

    // load dst chunk into LDS once; histogram from LDS
    for (int j = tid; j < n; j += P1_THREADS) {
        int d = eidx[start + j];
        dstc[j] = d;
        atomicAdd(&hcnt[d >> 8], 1);
    }
    __syncthreads();

    // reserve global space per bucket; cursor = global base within region
    if (tid < NB) {
        int c = hcnt[tid];
        hcur[tid] = (c > 0) ? atomicAdd(&gcnt[tid * GSTRIDE], c) : 0;
    }
    __syncthreads();

    // direct scatter: ~8-entry runs per (block,bucket); L2 merges writebacks
    for (int j = tid; j < n; j += P1_THREADS) {
        int dst = dstc[j];
        int src = eidx[N_EDGES + start + j];
        int b = dst >> 8;
        int p = atomicAdd(&hcur[b], 1);
        if (p < CAPB)
            buf[(unsigned)b * CAPB + (unsigned)p] =
                ((unsigned)src << 6) | ((unsigned)(dst & (NPB - 1)) << 24);
    }
}

// ---------------------------------------------------------------------------
// Pass 2: block = quarter of a coarse bucket (64 nodes). Filtered scatter
// into sentinel-padded 48-slot per-node LDS bins, count-balanced branchless
// DWORD gather (quarter-wave per node, 2 ch/lane, 8 loads in flight),
// bf16 h tile in LDS (unioned over dead bins), MFMA MLP, store.
// Grid = 4*NB = 1564; LDS 17.9KB -> 8 blocks/CU, all blocks co-resident.
// ---------------------------------------------------------------------------
__global__ __launch_bounds__(256, 8) void genconv_agg_mlp(
    const unsigned short* __restrict__ msgb,
    const int* __restrict__ gcnt,
    const unsigned* __restrict__ buf,
    const float* __restrict__ beta,
    const unsigned short* __restrict__ W1f,
    const unsigned short* __restrict__ W2f,
    const float* __restrict__ b1,
    const float* __restrict__ b2,
    float* __restrict__ out)          // [N,32]
{
    // bins (12288B, phase A: scatter+gather) unions with hid (9216B,
    // phase B: MFMA). Separated by the __syncthreads() after the gather.
    __shared__ __attribute__((aligned(16))) unsigned char pool[64 * SLOT * 4];
    unsigned* bins = (unsigned*)pool;                          // [64*SLOT]
    unsigned short* hid = (unsigned short*)pool;               // [4*16*72]
    __shared__ int hcnt[64];
    __shared__ int perm[64];                                   // rank -> node
    __shared__ __attribute__((aligned(16))) unsigned short sha[64 * 40];  // 5 KB

    // pre-fill bins with sentinel so over-read pads contribute exactly 0
    {
        uint4 sv = {SENT_OFF, SENT_OFF, SENT_OFF, SENT_OFF};
        for (int i = threadIdx.x; i < 64 * SLOT / 4; i += 256)
            ((uint4*)bins)[i] = sv;
        if (threadIdx.x < 64) hcnt[threadIdx.x] = 0;
    }
    __syncthreads();

    const int cb = blockIdx.x >> 2;            // coarse bucket 0..390
    const unsigned q = blockIdx.x & 3u;        // 64-node quarter
    const int cnt = min(gcnt[cb * GSTRIDE], CAPB);
    const unsigned* bp = buf + (size_t)cb * CAPB;

    // filtered single-pass scatter into per-node bins (pre-masked entries)
    {
        int nv = cnt & ~3;
        for (int i = threadIdx.x * 4; i < nv; i += 1024) {
            uint4 e4 = *(const uint4*)(bp + i);
#pragma unroll
            for (int u = 0; u < 4; ++u) {
                unsigned e = (u == 0) ? e4.x : (u == 1) ? e4.y : (u == 2) ? e4.z : e4.w;
                if ((e >> 30) == q) {
                    int ln = (e >> 24) & 63;
                    int p = atomicAdd(&hcnt[ln], 1);
                    if (p < SLOT) bins[ln * SLOT + p] = e & 0xFFFFFFu;
                }
            }
        }
        for (int i = nv + threadIdx.x; i < cnt; i += 256) {
            unsigned e = bp[i];
            if ((e >> 30) == q) {
                int ln = (e >> 24) & 63;
                int p = atomicAdd(&hcnt[ln], 1);
                if (p < SLOT) bins[ln * SLOT + p] = e & 0xFFFFFFu;
            }
        }
    }
    __syncthreads();

    // branch-free rank by count (desc): balanced wave assignment
    if (threadIdx.x < 64) {
        int c = hcnt[threadIdx.x];
        int r = 0;
#pragma unroll 8
        for (int j = 0; j < 64; ++j) {
            int cj = hcnt[j];
            r += (cj > c) || (cj == c && j < (int)threadIdx.x);
        }
        perm[r] = threadIdx.x;
    }
    __syncthreads();

    const int lane16 = threadIdx.x & 15;   // channel pair index (ch 2l,2l+1)
    const int qw = threadIdx.x >> 4;       // quarter-wave 0..15
    const int wvg = qw >> 2, qi = qw & 3;  // wave id, quarter within wave
    const float bl2 = beta[0] * 1.4426950408889634f;   // beta * log2(e)
    const unsigned loff = (unsigned)lane16 * 4u;       // channel-pair byte off
    const char* mb = (const char*)msgb;                // saddr base

    // dword dual-stream gather: 2 nodes/quarter-wave, 8 dwords in flight.
    // snake rank-windows: wave wvg -> windows {wvg, 7-wvg}; concurrent
    // nodes are rank-adjacent -> minimal divergence waste.
#pragma unroll
    for (int kp = 0; kp < 2; ++kp) {
        int window = kp ? (7 - wvg) : wvg;
        int s = window * 8 + qi * 2;
        int na = perm[s], nc = perm[s + 1];
        int ma = min(hcnt[na], SLOT);
        int mc = min(hcnt[nc], SLOT);
        int T = max((ma + 3) >> 2, (mc + 3) >> 2);
        const uint4* ba = (const uint4*)&bins[na * SLOT];
        const uint4* bc = (const uint4*)&bins[nc * SLOT];
        float seaL = 0.f, seaH = 0.f, smaL = 0.f, smaH = 0.f;
        float secL = 0.f, secH = 0.f, smcL = 0.f, smcH = 0.f;
        for (int t = 0; t < T; ++t) {
            uint4 ea = ba[t];                       // broadcast ds_read_b128
            uint4 ec = bc[t];
            unsigned da0 = *(const unsigned*)(mb + (ea.x + loff));
            unsigned da1 = *(const unsigned*)(mb + (ea.y + loff));
            unsigned da2 = *(const unsigned*)(mb + (ea.z + loff));
            unsigned da3 = *(const unsigned*)(mb + (ea.w + loff));
            unsigned dc0 = *(const unsigned*)(mb + (ec.x + loff));
            unsigned dc1 = *(const unsigned*)(mb + (ec.y + loff));
            unsigned dc2 = *(const unsigned*)(mb + (ec.z + loff));
            unsigned dc3 = *(const unsigned*)(mb + (ec.w + loff));
            // lo channel = bits 0-15, hi channel = bits 16-31
            float aL0 = __uint_as_float(da0 << 16), aH0 = __uint_as_float(da0 & 0xFFFF0000u);
            float aL1 = __uint_as_float(da1 << 16), aH1 = __uint_as_float(da1 & 0xFFFF0000u);
            float aL2 = __uint_as_float(da2 << 16), aH2 = __uint_as_float(da2 & 0xFFFF0000u);
            float aL3 = __uint_as_float(da3 << 16), aH3 = __uint_as_float(da3 & 0xFFFF0000u);
            float cL0 = __uint_as_float(dc0 << 16), cH0 = __uint_as_float(dc0 & 0xFFFF0000u);
            float cL1 = __uint_as_float(dc1 << 16), cH1 = __uint_as_float(dc1 & 0xFFFF0000u);
            float cL2 = __uint_as_float(dc2 << 16), cH2 = __uint_as_float(dc2 & 0xFFFF0000u);
            float cL3 = __uint_as_float(dc3 << 16), cH3 = __uint_as_float(dc3 & 0xFFFF0000u);
            float wL0 = __builtin_amdgcn_exp2f(bl2 * aL0);
            float wL1 = __builtin_amdgcn_exp2f(bl2 * aL1);
            float wL2 = __builtin_amdgcn_exp2f(bl2 * aL2);
            float wL3 = __builtin_amdgcn_exp2f(bl2 * aL3);
            float wH0 = __builtin_amdgcn_exp2f(bl2 * aH0);
            float wH1 = __builtin_amdgcn_exp2f(bl2 * aH1);
            float wH2 = __builtin_amdgcn_exp2f(bl2 * aH2);
            float wH3 = __builtin_amdgcn_exp2f(bl2 * aH3);
            float vL0 = __builtin_amdgcn_exp2f(bl2 * cL0);
            float vL1 = __builtin_amdgcn_exp2f(bl2 * cL1);
            float vL2 = __builtin_amdgcn_exp2f(bl2 * cL2);
            float vL3 = __builtin_amdgcn_exp2f(bl2 * cL3);
            float vH0 = __builtin_amdgcn_exp2f(bl2 * cH0);
            float vH1 = __builtin_amdgcn_exp2f(bl2 * cH1);
            float vH2 = __builtin_amdgcn_exp2f(bl2 * cH2);
            float vH3 = __builtin_amdgcn_exp2f(bl2 * cH3);
            seaL += (wL0 + wL1) + (wL2 + wL3);
            seaH += (wH0 + wH1) + (wH2 + wH3);
            secL += (vL0 + vL1) + (vL2 + vL3);
            secH += (vH0 + vH1) + (vH2 + vH3);
            smaL += wL0 * aL0 + wL1 * aL1 + wL2 * aL2 + wL3 * aL3;
            smaH += wH0 * aH0 + wH1 * aH1 + wH2 * aH2 + wH3 * aH3;
            smcL += vL0 * cL0 + vL1 * cL1 + vL2 * cL2 + vL3 * cL3;
            smcH += vH0 * cH0 + vH1 * cH1 + vH2 * cH2 + vH3 * cH3;
        }
        float haL = (seaL > 0.0f) ? (smaL / seaL) : 0.0f;
        float haH = (seaH > 0.0f) ? (smaH / seaH) : 0.0f;
        float hcL = (secL > 0.0f) ? (smcL / secL) : 0.0f;
        float hcH = (secH > 0.0f) ? (smcH / secH) : 0.0f;
        // packed ushort2 writes (byte offset node*80 + lane16*4, 4B aligned)
        *(unsigned*)&sha[na * 40 + lane16 * 2] =
            (unsigned)f2b(haL) | ((unsigned)f2b(haH) << 16);
        *(unsigned*)&sha[nc * 40 + lane16 * 2] =
            (unsigned)f2b(hcL) | ((unsigned)f2b(hcH) << 16);
    }
    __syncthreads();   // bins dead from here; pool reused as hid

    // ---- MFMA MLP: wave wv owns nodes [blockIdx.x*64 + wv*16, +16) ----
    const int wv = threadIdx.x >> 6;
    const int lane = threadIdx.x & 63;
    const int col = lane & 15, quad = lane >> 4;
    const int n0 = blockIdx.x * 64 + wv * 16;

    bf16x8 a = *(const bf16x8*)&sha[(wv * 16 + col) * 40 + quad * 8];

    const bf16x8* w1p = (const bf16x8*)W1f;
    f32x4 z = {0.f, 0.f, 0.f, 0.f};
    f32x4 c0 = __builtin_amdgcn_mfma_f32_16x16x32_bf16(a, w1p[0 * 64 + lane], z, 0, 0, 0);
    f32x4 c1 = __builtin_amdgcn_mfma_f32_16x16x32_bf16(a, w1p[1 * 64 + lane], z, 0, 0, 0);
    f32x4 c2 = __builtin_amdgcn_mfma_f32_16x16x32_bf16(a, w1p[2 * 64 + lane], z, 0, 0, 0);
    f32x4 c3 = __builtin_amdgcn_mfma_f32_16x16x32_bf16(a, w1p[3 * 64 + lane], z, 0, 0, 0);

    float bb0 = b1[col], bb1 = b1[16 + col], bb2 = b1[32 + col], bb3 = b1[48 + col];
    unsigned short* hrow = &hid[wv * 16 * 72];
#pragma unroll
    for (int r = 0; r < 4; ++r) {
        int row = quad * 4 + r;
        hrow[row * 72 + col]      = f2b(fmaxf(c0[r] + bb0, 0.f));
        hrow[row * 72 + 16 + col] = f2b(fmaxf(c1[r] + bb1, 0.f));
        hrow[row * 72 + 32 + col] = f2b(fmaxf(c2[r] + bb2, 0.f));
        hrow[row * 72 + 48 + col] = f2b(fmaxf(c3[r] + bb3, 0.f));
    }
    // per-wave LDS region: in-wave ordering suffices (r7-r14 precedent)

    bf16x8 h0 = *(const bf16x8*)&hrow[col * 72 + quad * 8];        // k 0..31
    bf16x8 h1 = *(const bf16x8*)&hrow[col * 72 + 32 + quad * 8];   // k 32..63

    const bf16x8* w2p = (const bf16x8*)W2f;
    f32x4 o0 = __builtin_amdgcn_mfma_f32_16x16x32_bf16(h0, w2p[0 * 64 + lane], z, 0, 0, 0);
    o0 = __builtin_amdgcn_mfma_f32_16x16x32_bf16(h1, w2p[1 * 64 + lane], o0, 0, 0, 0);
    f32x4 o1 = __builtin_amdgcn_mfma_f32_16x16x32_bf16(h0, w2p[2 * 64 + lane], z, 0, 0, 0);
    o1 = __builtin_amdgcn_mfma_f32_16x16x32_bf16(h1, w2p[3 * 64 + lane], o1, 0, 0, 0);

    float d0 = b2[col], d1 = b2[16 + col];
#pragma unroll
    for (int r = 0; r < 4; ++r) {
        int row = n0 + quad * 4 + r;
        if (row < N_NODES) {
            out[(size_t)row * DCH + col]      = o0[r] + d0;
            out[(size_t)row * DCH + 16 + col] = o1[r] + d1;
        }
    }
}

extern "C" void kernel_launch(void* const* d_in, const int* in_sizes, int n_in,
                              void* d_out, int out_size, void* d_ws, size_t ws_size,
                              hipStream_t stream) {
    const float* x    = (const float*)d_in[0];
    const int*   eidx = (const int*)d_in[1];
    const float* beta = (const float*)d_in[2];
    const float* W1   = (const float*)d_in[3];
    const float* b1   = (const float*)d_in[4];
    const float* W2   = (const float*)d_in[5];
    const float* b2   = (const float*)d_in[6];
    float* out = (float*)d_out;

    int* gcnt = (int*)d_ws;                                        // 25 KB
    unsigned* buf = (unsigned*)(gcnt + NB * GSTRIDE);              // 7.1 MB
    unsigned short* msgb = (unsigned short*)(buf + (size_t)NB * CAPB); // 6.4 MB + sentinel
    unsigned short* W1f = msgb + (size_t)(N_NODES + 1) * DCH;      // 4 KB
    unsigned short* W2f = W1f + 4 * 64 * 8;                        // 4 KB

    hipMemsetAsync(gcnt, 0, (size_t)NB * GSTRIDE * sizeof(int), stream);

    genconv_partition<<<P1_BLOCKS, P1_THREADS, 0, stream>>>(
        x, eidx, W1, W2, gcnt, buf, msgb, W1f, W2f);
    genconv_agg_mlp<<<4 * NB, 256, 0, stream>>>(msgb, gcnt, buf, beta,
                                                W1f, W2f, b1, b2, out);
}